// Round 2
// baseline (254.535 us; speedup 1.0000x reference)
//
#include <hip/hip_runtime.h>
#include <hip/hip_bf16.h>

typedef _Float16 f16;
typedef f16 f16x8 __attribute__((ext_vector_type(8)));
typedef f16 f16x4 __attribute__((ext_vector_type(4)));
typedef float f32x4 __attribute__((ext_vector_type(4)));

#define MFMA_F16(a, b, c) __builtin_amdgcn_mfma_f32_16x16x32_f16((a), (b), (c), 0, 0, 0)

// ---------------------------------------------------------------------------
// async global->LDS 16B copy
// ---------------------------------------------------------------------------
__device__ __forceinline__ void ld_lds16(const void* g, void* l) {
  __builtin_amdgcn_global_load_lds((const __attribute__((address_space(1))) void*)g,
                                   (__attribute__((address_space(3))) void*)l, 16, 0, 0);
}

// ---------------------------------------------------------------------------
// cast fp32 -> fp16 for hidden (2M) + 4 weight matrices (1M each), float4-wide
// ---------------------------------------------------------------------------
__global__ __launch_bounds__(256) void cast_all(
    const float* __restrict__ hs, const float* __restrict__ wq,
    const float* __restrict__ wk, const float* __restrict__ wv,
    const float* __restrict__ wo, f16* __restrict__ hb,
    f16* __restrict__ wqb, f16* __restrict__ wkb,
    f16* __restrict__ wvb, f16* __restrict__ wob) {
  int idx = blockIdx.x * 256 + threadIdx.x;  // 1,572,864 float4 chunks total
  const float* src;
  f16* dst;
  int j;
  if (idx < 524288) {  // hidden: 2M floats / 4
    src = hs; dst = hb; j = idx;
  } else {
    int t = idx - 524288;
    int w = t >> 18;      // 262144 float4 per weight
    j = t & 262143;
    src = (w == 0) ? wq : (w == 1) ? wk : (w == 2) ? wv : wo;
    dst = (w == 0) ? wqb : (w == 1) ? wkb : (w == 2) ? wvb : wob;
  }
  float4 v = ((const float4*)src)[j];
  f16x4 o;
  o[0] = (f16)v.x; o[1] = (f16)v.y; o[2] = (f16)v.z; o[3] = (f16)v.w;
  ((f16x4*)dst)[j] = o;
}

// ---------------------------------------------------------------------------
// relative-position bias table: btab[h][rel + 2047], rel = kv - q
// ---------------------------------------------------------------------------
__global__ __launch_bounds__(256) void build_bias(const float* __restrict__ rb,
                                                  float* __restrict__ btab) {
  int idx = blockIdx.x * 256 + threadIdx.x;  // 65536 = 16 heads * 4096
  int h = idx >> 12;
  int t = idx & 4095;
  int rel = t - 2047;
  int bucket = (rel > 0) ? 16 : 0;
  int a = (rel < 0) ? -rel : rel;
  int lg;
  if (a < 8) {
    lg = a;
  } else {
    int cnt = (a >= 12) + (a >= 16) + (a >= 23) + (a >= 32) + (a >= 46) +
              (a >= 64) + (a >= 91);
    lg = 8 + cnt;  // max 15
  }
  bucket += lg;
  btab[idx] = rb[bucket * 16 + h];  // rel_bias[32][16]
}

// ---------------------------------------------------------------------------
// GEMM mainloop: C[128x128] tile of A[M,K=1024] * B[N,K=1024]^T (both row-major)
// 256 threads = 4 waves (2x2), each wave 64x64 = 4x4 MFMA frags, BK=32
// ---------------------------------------------------------------------------
__device__ __forceinline__ void gemm_mainloop(const f16* __restrict__ A,
                                              const f16* __restrict__ B,
                                              int brow, int bcol,
                                              f16* lA, f16* lB,
                                              f32x4 acc[4][4]) {
  const int tid = threadIdx.x;
  const int lane = tid & 63;
  const int wave = tid >> 6;
  const int wm = wave >> 1, wn = wave & 1;
  const int lo = lane & 15;
  const int hi8 = (lane >> 4) << 3;
  const f16* ga = A + (size_t)(brow + (tid >> 2)) * 1024 + ((tid & 3) << 3);
  const f16* gb = B + (size_t)(bcol + (tid >> 2)) * 1024 + ((tid & 3) << 3);
  f16* la_dst = lA + tid * 8;
  f16* lb_dst = lB + tid * 8;
  for (int k0 = 0; k0 < 1024; k0 += 32) {
    ld_lds16(ga + k0,             la_dst);
    ld_lds16(ga + k0 + 64 * 1024, la_dst + 2048);
    ld_lds16(gb + k0,             lb_dst);
    ld_lds16(gb + k0 + 64 * 1024, lb_dst + 2048);
    __syncthreads();
    f16x8 af[4], bf[4];
#pragma unroll
    for (int i = 0; i < 4; ++i) {
      af[i] = *(const f16x8*)(lA + (wm * 64 + i * 16 + lo) * 32 + hi8);
      bf[i] = *(const f16x8*)(lB + (wn * 64 + i * 16 + lo) * 32 + hi8);
    }
#pragma unroll
    for (int i = 0; i < 4; ++i)
#pragma unroll
      for (int j = 0; j < 4; ++j)
        acc[i][j] = MFMA_F16(af[i], bf[j], acc[i][j]);
    __syncthreads();
  }
}

// QKV projections fused over blockIdx.z (0=Q, 1=K, 2=V-transposed)
__global__ __launch_bounds__(256) void gemm_qkv(
    const f16* __restrict__ A, const f16* __restrict__ Wq,
    const f16* __restrict__ Wk, const f16* __restrict__ Wv,
    f16* __restrict__ Qo, f16* __restrict__ Ko, f16* __restrict__ VTo) {
  __shared__ __align__(16) f16 lA[128 * 32];
  __shared__ __align__(16) f16 lB[128 * 32];
  const int z = blockIdx.z;
  const f16* B = (z == 0) ? Wq : (z == 1) ? Wk : Wv;
  const int brow = blockIdx.x * 128, bcol = blockIdx.y * 128;
  f32x4 acc[4][4];
#pragma unroll
  for (int i = 0; i < 4; ++i)
#pragma unroll
    for (int j = 0; j < 4; ++j) acc[i][j] = f32x4{0.f, 0.f, 0.f, 0.f};
  gemm_mainloop(A, B, brow, bcol, lA, lB, acc);
  const int lane = threadIdx.x & 63, wave = threadIdx.x >> 6;
  const int wm = wave >> 1, wn = wave & 1;
  const int lo = lane & 15, hi = lane >> 4;
  if (z < 2) {
    f16* C = z ? Ko : Qo;
#pragma unroll
    for (int i = 0; i < 4; ++i)
#pragma unroll
      for (int j = 0; j < 4; ++j) {
        int col = bcol + wn * 64 + j * 16 + lo;
        int row0 = brow + wm * 64 + i * 16 + hi * 4;
#pragma unroll
        for (int r = 0; r < 4; ++r)
          C[(size_t)(row0 + r) * 1024 + col] = (f16)acc[i][j][r];
      }
  } else {
    // V transposed: VT[n][s], n = h*64+dv
#pragma unroll
    for (int i = 0; i < 4; ++i)
#pragma unroll
      for (int j = 0; j < 4; ++j) {
        int col = bcol + wn * 64 + j * 16 + lo;       // n
        int row0 = brow + wm * 64 + i * 16 + hi * 4;  // s
        f16x4 v4;
#pragma unroll
        for (int r = 0; r < 4; ++r) v4[r] = (f16)acc[i][j][r];
        *(f16x4*)(VTo + (size_t)col * 2048 + row0) = v4;
      }
  }
}

// output projection: AO[2048,1024] * Wo[1024,1024]^T -> fp32 d_out
__global__ __launch_bounds__(256) void gemm_out(const f16* __restrict__ A,
                                                const f16* __restrict__ W,
                                                float* __restrict__ C) {
  __shared__ __align__(16) f16 lA[128 * 32];
  __shared__ __align__(16) f16 lB[128 * 32];
  const int brow = blockIdx.x * 128, bcol = blockIdx.y * 128;
  f32x4 acc[4][4];
#pragma unroll
  for (int i = 0; i < 4; ++i)
#pragma unroll
    for (int j = 0; j < 4; ++j) acc[i][j] = f32x4{0.f, 0.f, 0.f, 0.f};
  gemm_mainloop(A, W, brow, bcol, lA, lB, acc);
  const int lane = threadIdx.x & 63, wave = threadIdx.x >> 6;
  const int wm = wave >> 1, wn = wave & 1;
  const int lo = lane & 15, hi = lane >> 4;
#pragma unroll
  for (int i = 0; i < 4; ++i)
#pragma unroll
    for (int j = 0; j < 4; ++j) {
      int col = bcol + wn * 64 + j * 16 + lo;
      int row0 = brow + wm * 64 + i * 16 + hi * 4;
#pragma unroll
      for (int r = 0; r < 4; ++r)
        C[(size_t)(row0 + r) * 1024 + col] = acc[i][j][r];
    }
}

// ---------------------------------------------------------------------------
// Flash attention with T5 relative bias — KV-split across waves for occupancy.
// Block = (head, 16 q-rows); 4 waves each handle a 512-wide KV quarter with
// online softmax, then merge partial (m, l, O) exactly in LDS.
// Swapped QK^T: S^T[kv][q] = mfma(K_rows, Q^T) -> softmax lane-local per q.
// PV uses k-map g2(l,j) = (j>>2)*16 + (lane>>4)*4 + (j&3) on BOTH operands.
// ---------------------------------------------------------------------------
__global__ __launch_bounds__(256, 8) void attn_kernel(
    const f16* __restrict__ Q, const f16* __restrict__ K,
    const f16* __restrict__ VT, const float* __restrict__ btab,
    f16* __restrict__ AO) {
  __shared__ float lsO[4][64][16];  // [wave][dv][q] 16 KB
  __shared__ float lsM[4][16];
  __shared__ float lsL[4][16];

  const int h = blockIdx.y;
  const int q0 = blockIdx.x * 16;
  const int tid = threadIdx.x;
  const int wave = tid >> 6, lane = tid & 63;
  const int lo = lane & 15, hi = lane >> 4;
  const int myq = q0 + lo;  // this lane's q column (same q-set for all waves)

  // Q fragments (B-operand, cols = q): held in registers for whole kernel
  f16x8 qf[2];
#pragma unroll
  for (int kk = 0; kk < 2; ++kk)
    qf[kk] = *(const f16x8*)(Q + (size_t)myq * 1024 + h * 64 + kk * 32 + hi * 8);

  float m_run = -1e30f, l_run = 0.f;
  f32x4 oacc[4];
#pragma unroll
  for (int d = 0; d < 4; ++d) oacc[d] = f32x4{0.f, 0.f, 0.f, 0.f};

  const float* bt = btab + h * 4096 + 2047 - myq;
  const f16* Kh = K + h * 64;
  const f16* VTh = VT + (size_t)h * 64 * 2048;

  const int kv_begin = wave * 512;
  const int kv_end = kv_begin + 512;
  for (int kv0 = kv_begin; kv0 < kv_end; kv0 += 64) {
    // ---- scores S^T (4 frags over kv) ----
    f32x4 sacc[4];
#pragma unroll
    for (int m = 0; m < 4; ++m) sacc[m] = f32x4{0.f, 0.f, 0.f, 0.f};
#pragma unroll
    for (int m = 0; m < 4; ++m) {
#pragma unroll
      for (int kk = 0; kk < 2; ++kk) {
        f16x8 kf = *(const f16x8*)(Kh + (size_t)(kv0 + m * 16 + lo) * 1024 +
                                   kk * 32 + hi * 8);
        sacc[m] = MFMA_F16(kf, qf[kk], sacc[m]);
      }
    }
    // ---- bias + online softmax (per lane: fixed q=myq, 16 kv values) ----
    float p[16];
    float mx = -1e30f;
#pragma unroll
    for (int m = 0; m < 4; ++m)
#pragma unroll
      for (int r = 0; r < 4; ++r) {
        int kv = kv0 + m * 16 + hi * 4 + r;
        float s = sacc[m][r] + bt[kv];
        p[m * 4 + r] = s;
        mx = fmaxf(mx, s);
      }
    mx = fmaxf(mx, __shfl_xor(mx, 16, 64));
    mx = fmaxf(mx, __shfl_xor(mx, 32, 64));
    float m_new = fmaxf(m_run, mx);
    float scale = __expf(m_run - m_new);
    float psum = 0.f;
#pragma unroll
    for (int i = 0; i < 16; ++i) {
      p[i] = __expf(p[i] - m_new);
      psum += p[i];
    }
    psum += __shfl_xor(psum, 16, 64);
    psum += __shfl_xor(psum, 32, 64);
    l_run = l_run * scale + psum;
    m_run = m_new;
#pragma unroll
    for (int d = 0; d < 4; ++d) oacc[d] *= scale;
    // ---- P -> f16 fragments (B-operand of PV, k-map g2) ----
    f16x8 pf[2];
#pragma unroll
    for (int kk = 0; kk < 2; ++kk)
#pragma unroll
      for (int j = 0; j < 8; ++j)
        pf[kk][j] = (f16)p[(kk * 2 + (j >> 2)) * 4 + (j & 3)];
    // ---- PV: A-operand = V^T rows with same k-map g2 ----
#pragma unroll
    for (int d = 0; d < 4; ++d) {
#pragma unroll
      for (int kk = 0; kk < 2; ++kk) {
        const f16* vp = VTh + (size_t)(d * 16 + lo) * 2048 + kv0 + kk * 32 + hi * 4;
        f16x4 v_lo = *(const f16x4*)(vp);
        f16x4 v_hi = *(const f16x4*)(vp + 16);
        f16x8 vf;
#pragma unroll
        for (int r = 0; r < 4; ++r) { vf[r] = v_lo[r]; vf[r + 4] = v_hi[r]; }
        oacc[d] = MFMA_F16(vf, pf[kk], oacc[d]);
      }
    }
  }

  // ---- write partial state to LDS ----
  if (hi == 0) {
    lsM[wave][lo] = m_run;
    lsL[wave][lo] = l_run;
  }
#pragma unroll
  for (int d = 0; d < 4; ++d)
#pragma unroll
    for (int r = 0; r < 4; ++r)
      lsO[wave][d * 16 + hi * 4 + r][lo] = oacc[d][r];
  __syncthreads();

  // ---- exact merge across the 4 KV quarters + epilogue ----
  {
    const int q = tid & 15;
    const int dq = tid >> 4;  // 0..15, covers dv block of 4
    float m0 = lsM[0][q], m1 = lsM[1][q], m2 = lsM[2][q], m3 = lsM[3][q];
    float M = fmaxf(fmaxf(m0, m1), fmaxf(m2, m3));
    float e0 = __expf(m0 - M), e1 = __expf(m1 - M);
    float e2 = __expf(m2 - M), e3 = __expf(m3 - M);
    float L = lsL[0][q] * e0 + lsL[1][q] * e1 + lsL[2][q] * e2 + lsL[3][q] * e3;
    float inv = 1.f / L;
    f16x4 ov;
#pragma unroll
    for (int j = 0; j < 4; ++j) {
      int dv = dq * 4 + j;
      float o = lsO[0][dv][q] * e0 + lsO[1][dv][q] * e1 +
                lsO[2][dv][q] * e2 + lsO[3][dv][q] * e3;
      ov[j] = (f16)(o * inv);
    }
    *(f16x4*)(AO + (size_t)(q0 + q) * 1024 + h * 64 + dq * 4) = ov;
  }
}

// ---------------------------------------------------------------------------
extern "C" void kernel_launch(void* const* d_in, const int* in_sizes, int n_in,
                              void* d_out, int out_size, void* d_ws, size_t ws_size,
                              hipStream_t stream) {
  const float* hs = (const float*)d_in[0];
  const float* wq = (const float*)d_in[1];
  const float* wk = (const float*)d_in[2];
  const float* wv = (const float*)d_in[3];
  const float* wo = (const float*)d_in[4];
  const float* rb = (const float*)d_in[5];

  char* w = (char*)d_ws;
  f16* hb  = (f16*)w; w += (size_t)2048 * 1024 * 2;
  f16* wqb = (f16*)w; w += (size_t)1024 * 1024 * 2;
  f16* wkb = (f16*)w; w += (size_t)1024 * 1024 * 2;
  f16* wvb = (f16*)w; w += (size_t)1024 * 1024 * 2;
  f16* wob = (f16*)w; w += (size_t)1024 * 1024 * 2;
  f16* Qb  = (f16*)w; w += (size_t)2048 * 1024 * 2;
  f16* Kb  = (f16*)w; w += (size_t)2048 * 1024 * 2;
  f16* VTb = (f16*)w; w += (size_t)2048 * 1024 * 2;
  f16* AOb = (f16*)w; w += (size_t)2048 * 1024 * 2;
  float* btab = (float*)w; w += (size_t)16 * 4096 * 4;

  cast_all<<<6144, 256, 0, stream>>>(hs, wq, wk, wv, wo, hb, wqb, wkb, wvb, wob);
  build_bias<<<256, 256, 0, stream>>>(rb, btab);
  gemm_qkv<<<dim3(16, 8, 3), 256, 0, stream>>>(hb, wqb, wkb, wvb, Qb, Kb, VTb);
  attn_kernel<<<dim3(128, 16), 256, 0, stream>>>(Qb, Kb, VTb, btab, AOb);
  gemm_out<<<dim3(16, 8), 256, 0, stream>>>(AOb, wob, (float*)d_out);
}

// Round 3
// 109.842 us; speedup vs baseline: 2.3173x; 2.3173x over previous
//
#include <hip/hip_runtime.h>
#include <hip/hip_bf16.h>

typedef _Float16 f16;
typedef f16 f16x8 __attribute__((ext_vector_type(8)));
typedef f16 f16x4 __attribute__((ext_vector_type(4)));
typedef float f32x4 __attribute__((ext_vector_type(4)));

#define MFMA_F16(a, b, c) __builtin_amdgcn_mfma_f32_16x16x32_f16((a), (b), (c), 0, 0, 0)

// ---------------------------------------------------------------------------
// async global->LDS 16B copy (wave-uniform base + lane*16; we pass per-lane
// ptr = base + lane*16 which matches the HW mapping)
// ---------------------------------------------------------------------------
__device__ __forceinline__ void ld_lds16(const void* g, void* l) {
  __builtin_amdgcn_global_load_lds((const __attribute__((address_space(1))) void*)g,
                                   (__attribute__((address_space(3))) void*)l, 16, 0, 0);
}

// ---------------------------------------------------------------------------
// cast fp32 -> fp16 for hidden (2M) + 4 weight matrices (1M each), float4-wide
// ---------------------------------------------------------------------------
__global__ __launch_bounds__(256) void cast_all(
    const float* __restrict__ hs, const float* __restrict__ wq,
    const float* __restrict__ wk, const float* __restrict__ wv,
    const float* __restrict__ wo, f16* __restrict__ hb,
    f16* __restrict__ wqb, f16* __restrict__ wkb,
    f16* __restrict__ wvb, f16* __restrict__ wob) {
  int idx = blockIdx.x * 256 + threadIdx.x;  // 1,572,864 float4 chunks total
  const float* src;
  f16* dst;
  int j;
  if (idx < 524288) {  // hidden: 2M floats / 4
    src = hs; dst = hb; j = idx;
  } else {
    int t = idx - 524288;
    int w = t >> 18;      // 262144 float4 per weight
    j = t & 262143;
    src = (w == 0) ? wq : (w == 1) ? wk : (w == 2) ? wv : wo;
    dst = (w == 0) ? wqb : (w == 1) ? wkb : (w == 2) ? wvb : wob;
  }
  float4 v = ((const float4*)src)[j];
  f16x4 o;
  o[0] = (f16)v.x; o[1] = (f16)v.y; o[2] = (f16)v.z; o[3] = (f16)v.w;
  ((f16x4*)dst)[j] = o;
}

// ---------------------------------------------------------------------------
// relative-position bias table: btab[h][rel + 2047], rel = kv - q
// ---------------------------------------------------------------------------
__global__ __launch_bounds__(256) void build_bias(const float* __restrict__ rb,
                                                  float* __restrict__ btab) {
  int idx = blockIdx.x * 256 + threadIdx.x;  // 65536 = 16 heads * 4096
  int h = idx >> 12;
  int t = idx & 4095;
  int rel = t - 2047;
  int bucket = (rel > 0) ? 16 : 0;
  int a = (rel < 0) ? -rel : rel;
  int lg;
  if (a < 8) {
    lg = a;
  } else {
    int cnt = (a >= 12) + (a >= 16) + (a >= 23) + (a >= 32) + (a >= 46) +
              (a >= 64) + (a >= 91);
    lg = 8 + cnt;  // max 15
  }
  bucket += lg;
  btab[idx] = rb[bucket * 16 + h];  // rel_bias[32][16]
}

// ---------------------------------------------------------------------------
// GEMM mainloop: C[128x128] tile of A[M,K=1024] * B[N,K=1024]^T (both row-major)
// ---------------------------------------------------------------------------
__device__ __forceinline__ void gemm_mainloop(const f16* __restrict__ A,
                                              const f16* __restrict__ B,
                                              int brow, int bcol,
                                              f16* lA, f16* lB,
                                              f32x4 acc[4][4]) {
  const int tid = threadIdx.x;
  const int lane = tid & 63;
  const int wave = tid >> 6;
  const int wm = wave >> 1, wn = wave & 1;
  const int lo = lane & 15;
  const int hi8 = (lane >> 4) << 3;
  const f16* ga = A + (size_t)(brow + (tid >> 2)) * 1024 + ((tid & 3) << 3);
  const f16* gb = B + (size_t)(bcol + (tid >> 2)) * 1024 + ((tid & 3) << 3);
  f16* la_dst = lA + tid * 8;
  f16* lb_dst = lB + tid * 8;
  for (int k0 = 0; k0 < 1024; k0 += 32) {
    ld_lds16(ga + k0,             la_dst);
    ld_lds16(ga + k0 + 64 * 1024, la_dst + 2048);
    ld_lds16(gb + k0,             lb_dst);
    ld_lds16(gb + k0 + 64 * 1024, lb_dst + 2048);
    __syncthreads();
    f16x8 af[4], bf[4];
#pragma unroll
    for (int i = 0; i < 4; ++i) {
      af[i] = *(const f16x8*)(lA + (wm * 64 + i * 16 + lo) * 32 + hi8);
      bf[i] = *(const f16x8*)(lB + (wn * 64 + i * 16 + lo) * 32 + hi8);
    }
#pragma unroll
    for (int i = 0; i < 4; ++i)
#pragma unroll
      for (int j = 0; j < 4; ++j)
        acc[i][j] = MFMA_F16(af[i], bf[j], acc[i][j]);
    __syncthreads();
  }
}

// QKV projections fused over blockIdx.z (0=Q, 1=K, 2=V-transposed)
__global__ __launch_bounds__(256) void gemm_qkv(
    const f16* __restrict__ A, const f16* __restrict__ Wq,
    const f16* __restrict__ Wk, const f16* __restrict__ Wv,
    f16* __restrict__ Qo, f16* __restrict__ Ko, f16* __restrict__ VTo) {
  __shared__ __align__(16) f16 lA[128 * 32];
  __shared__ __align__(16) f16 lB[128 * 32];
  const int z = blockIdx.z;
  const f16* B = (z == 0) ? Wq : (z == 1) ? Wk : Wv;
  const int brow = blockIdx.x * 128, bcol = blockIdx.y * 128;
  f32x4 acc[4][4];
#pragma unroll
  for (int i = 0; i < 4; ++i)
#pragma unroll
    for (int j = 0; j < 4; ++j) acc[i][j] = f32x4{0.f, 0.f, 0.f, 0.f};
  gemm_mainloop(A, B, brow, bcol, lA, lB, acc);
  const int lane = threadIdx.x & 63, wave = threadIdx.x >> 6;
  const int wm = wave >> 1, wn = wave & 1;
  const int lo = lane & 15, hi = lane >> 4;
  if (z < 2) {
    f16* C = z ? Ko : Qo;
#pragma unroll
    for (int i = 0; i < 4; ++i)
#pragma unroll
      for (int j = 0; j < 4; ++j) {
        int col = bcol + wn * 64 + j * 16 + lo;
        int row0 = brow + wm * 64 + i * 16 + hi * 4;
#pragma unroll
        for (int r = 0; r < 4; ++r)
          C[(size_t)(row0 + r) * 1024 + col] = (f16)acc[i][j][r];
      }
  } else {
    // V transposed: VT[n][s], n = h*64+dv
#pragma unroll
    for (int i = 0; i < 4; ++i)
#pragma unroll
      for (int j = 0; j < 4; ++j) {
        int col = bcol + wn * 64 + j * 16 + lo;       // n
        int row0 = brow + wm * 64 + i * 16 + hi * 4;  // s
        f16x4 v4;
#pragma unroll
        for (int r = 0; r < 4; ++r) v4[r] = (f16)acc[i][j][r];
        *(f16x4*)(VTo + (size_t)col * 2048 + row0) = v4;
      }
  }
}

// output projection: AO[2048,1024] * Wo[1024,1024]^T -> fp32 d_out
__global__ __launch_bounds__(256) void gemm_out(const f16* __restrict__ A,
                                                const f16* __restrict__ W,
                                                float* __restrict__ C) {
  __shared__ __align__(16) f16 lA[128 * 32];
  __shared__ __align__(16) f16 lB[128 * 32];
  const int brow = blockIdx.x * 128, bcol = blockIdx.y * 128;
  f32x4 acc[4][4];
#pragma unroll
  for (int i = 0; i < 4; ++i)
#pragma unroll
    for (int j = 0; j < 4; ++j) acc[i][j] = f32x4{0.f, 0.f, 0.f, 0.f};
  gemm_mainloop(A, W, brow, bcol, lA, lB, acc);
  const int lane = threadIdx.x & 63, wave = threadIdx.x >> 6;
  const int wm = wave >> 1, wn = wave & 1;
  const int lo = lane & 15, hi = lane >> 4;
#pragma unroll
  for (int i = 0; i < 4; ++i)
#pragma unroll
    for (int j = 0; j < 4; ++j) {
      int col = bcol + wn * 64 + j * 16 + lo;
      int row0 = brow + wm * 64 + i * 16 + hi * 4;
#pragma unroll
      for (int r = 0; r < 4; ++r)
        C[(size_t)(row0 + r) * 1024 + col] = acc[i][j][r];
    }
}

// ---------------------------------------------------------------------------
// Flash attention v3: LDS-staged K/V tiles, double-buffered, XOR-swizzled.
// Block = (head, 64 q-rows); 4 waves x 16 q-rows share each staged tile.
// K tile [64 kv][64 d], V tile [64 dv][64 kv], both as 8x16B chunks/row with
// chunk' = chunk ^ (row&7) applied on the GLOBAL source (stage) and on the
// LDS read (both-sides swizzle; global_load_lds writes linearly).
// Swapped QK^T: S^T[kv][q] = mfma(K_rows, Q^T) -> softmax lane-local per q.
// ---------------------------------------------------------------------------
__global__ __launch_bounds__(256, 2) void attn_kernel(
    const f16* __restrict__ Q, const f16* __restrict__ K,
    const f16* __restrict__ VT, const float* __restrict__ btab,
    f16* __restrict__ AO) {
  __shared__ __align__(16) f16 lK[2][4096];
  __shared__ __align__(16) f16 lV[2][4096];

  const int h = blockIdx.y;
  const int q0 = blockIdx.x * 64;
  const int tid = threadIdx.x;
  const int wave = tid >> 6, lane = tid & 63;
  const int lo = lane & 15, hi = lane >> 4;
  const int sw = lo & 7;               // read-side swizzle key (row&7 == lo&7)
  const int myq = q0 + wave * 16 + lo;

  const f16* Kh = K + h * 64;
  const f16* VTh = VT + (size_t)h * 64 * 2048;
  const float* bt = btab + h * 4096 + 2047 - myq;

  // Q fragments (B-operand, cols = q): registers for whole kernel
  f16x8 qf[2];
#pragma unroll
  for (int kk = 0; kk < 2; ++kk)
    qf[kk] = *(const f16x8*)(Q + (size_t)myq * 1024 + h * 64 + kk * 32 + hi * 8);

  // staging chunk indices for this thread (2 chunks each for K and V)
  const int sc0 = wave * 64 + lane;   // chunk 0..255
  const int sc1 = 256 + sc0;          // chunk 256..511
  const int r0 = sc0 >> 3, e0 = (sc0 & 7) ^ (r0 & 7);
  const int r1 = sc1 >> 3, e1 = (sc1 & 7) ^ (r1 & 7);

#define STAGE(bufi, kv)                                                        \
  do {                                                                         \
    ld_lds16(Kh + (size_t)((kv) + r0) * 1024 + e0 * 8, &lK[bufi][sc0 * 8]);    \
    ld_lds16(Kh + (size_t)((kv) + r1) * 1024 + e1 * 8, &lK[bufi][sc1 * 8]);    \
    ld_lds16(VTh + (size_t)r0 * 2048 + (kv) + e0 * 8, &lV[bufi][sc0 * 8]);     \
    ld_lds16(VTh + (size_t)r1 * 2048 + (kv) + e1 * 8, &lV[bufi][sc1 * 8]);     \
  } while (0)

  float m_run = -1e30f, l_run = 0.f;
  f32x4 oacc[4];
#pragma unroll
  for (int d = 0; d < 4; ++d) oacc[d] = f32x4{0.f, 0.f, 0.f, 0.f};

  STAGE(0, 0);
  __syncthreads();

  for (int t = 0; t < 32; ++t) {
    const int kv0 = t * 64;
    const int b = t & 1;
    if (t < 31) STAGE(b ^ 1, kv0 + 64);

    // bias for this tile into registers (independent loads, early issue)
    float bias[16];
#pragma unroll
    for (int m = 0; m < 4; ++m)
#pragma unroll
      for (int r = 0; r < 4; ++r)
        bias[m * 4 + r] = bt[kv0 + m * 16 + hi * 4 + r];

    // ---- scores S^T (4 frags over kv) from swizzled LDS ----
    f32x4 sacc[4];
#pragma unroll
    for (int m = 0; m < 4; ++m) sacc[m] = f32x4{0.f, 0.f, 0.f, 0.f};
#pragma unroll
    for (int m = 0; m < 4; ++m)
#pragma unroll
      for (int kk = 0; kk < 2; ++kk) {
        f16x8 kf = *(const f16x8*)(&lK[b][(m * 16 + lo) * 64 +
                                          (((kk << 2) | hi) ^ sw) * 8]);
        sacc[m] = MFMA_F16(kf, qf[kk], sacc[m]);
      }

    // ---- bias + online softmax (per lane: fixed q=myq, 16 kv values) ----
    float p[16];
    float mx = -1e30f;
#pragma unroll
    for (int i = 0; i < 16; ++i) {
      float s = sacc[i >> 2][i & 3] + bias[i];
      p[i] = s;
      mx = fmaxf(mx, s);
    }
    mx = fmaxf(mx, __shfl_xor(mx, 16, 64));
    mx = fmaxf(mx, __shfl_xor(mx, 32, 64));
    float m_new = fmaxf(m_run, mx);
    float scale = __expf(m_run - m_new);
    float psum = 0.f;
#pragma unroll
    for (int i = 0; i < 16; ++i) {
      p[i] = __expf(p[i] - m_new);
      psum += p[i];
    }
    psum += __shfl_xor(psum, 16, 64);
    psum += __shfl_xor(psum, 32, 64);
    l_run = l_run * scale + psum;
    m_run = m_new;
#pragma unroll
    for (int d = 0; d < 4; ++d) oacc[d] *= scale;

    // ---- P -> f16 fragments (B-operand of PV, k-map g2) ----
    f16x8 pf[2];
#pragma unroll
    for (int kk = 0; kk < 2; ++kk)
#pragma unroll
      for (int j = 0; j < 8; ++j)
        pf[kk][j] = (f16)p[(kk * 2 + (j >> 2)) * 4 + (j & 3)];

    // ---- PV: A-operand = V^T rows (swizzled LDS), same k-map g2 ----
#pragma unroll
    for (int d = 0; d < 4; ++d)
#pragma unroll
      for (int kk = 0; kk < 2; ++kk) {
        const int row = d * 16 + lo;
        const int cc = kk * 4 + (hi >> 1);
        const int ia = (hi & 1) * 4;
        f16x4 v_lo = *(const f16x4*)(&lV[b][row * 64 + (cc ^ sw) * 8 + ia]);
        f16x4 v_hi = *(const f16x4*)(&lV[b][row * 64 + ((cc + 2) ^ sw) * 8 + ia]);
        f16x8 vf;
#pragma unroll
        for (int r = 0; r < 4; ++r) { vf[r] = v_lo[r]; vf[r + 4] = v_hi[r]; }
        oacc[d] = MFMA_F16(vf, pf[kk], oacc[d]);
      }

    __syncthreads();  // staged buffer ready (vmcnt drain) + tile b free
  }
#undef STAGE

  // ---- epilogue: O[dv][q] / l -> AO[s][h*64+dv] ----
  float inv = 1.f / l_run;
#pragma unroll
  for (int d = 0; d < 4; ++d) {
    f16x4 ov;
#pragma unroll
    for (int r = 0; r < 4; ++r) ov[r] = (f16)(oacc[d][r] * inv);
    *(f16x4*)(AO + (size_t)myq * 1024 + h * 64 + d * 16 + hi * 4) = ov;
  }
}

// ---------------------------------------------------------------------------
extern "C" void kernel_launch(void* const* d_in, const int* in_sizes, int n_in,
                              void* d_out, int out_size, void* d_ws, size_t ws_size,
                              hipStream_t stream) {
  const float* hs = (const float*)d_in[0];
  const float* wq = (const float*)d_in[1];
  const float* wk = (const float*)d_in[2];
  const float* wv = (const float*)d_in[3];
  const float* wo = (const float*)d_in[4];
  const float* rb = (const float*)d_in[5];

  char* w = (char*)d_ws;
  f16* hb  = (f16*)w; w += (size_t)2048 * 1024 * 2;
  f16* wqb = (f16*)w; w += (size_t)1024 * 1024 * 2;
  f16* wkb = (f16*)w; w += (size_t)1024 * 1024 * 2;
  f16* wvb = (f16*)w; w += (size_t)1024 * 1024 * 2;
  f16* wob = (f16*)w; w += (size_t)1024 * 1024 * 2;
  f16* Qb  = (f16*)w; w += (size_t)2048 * 1024 * 2;
  f16* Kb  = (f16*)w; w += (size_t)2048 * 1024 * 2;
  f16* VTb = (f16*)w; w += (size_t)2048 * 1024 * 2;
  f16* AOb = (f16*)w; w += (size_t)2048 * 1024 * 2;
  float* btab = (float*)w; w += (size_t)16 * 4096 * 4;

  cast_all<<<6144, 256, 0, stream>>>(hs, wq, wk, wv, wo, hb, wqb, wkb, wvb, wob);
  build_bias<<<256, 256, 0, stream>>>(rb, btab);
  gemm_qkv<<<dim3(16, 8, 3), 256, 0, stream>>>(hb, wqb, wkb, wvb, Qb, Kb, VTb);
  attn_kernel<<<dim3(32, 16), 256, 0, stream>>>(Qb, Kb, VTb, btab, AOb);
  gemm_out<<<dim3(16, 8), 256, 0, stream>>>(AOb, wob, (float*)d_out);
}

// Round 4
// 109.138 us; speedup vs baseline: 2.3322x; 1.0064x over previous
//
#include <hip/hip_runtime.h>
#include <hip/hip_bf16.h>

typedef _Float16 f16;
typedef f16 f16x8 __attribute__((ext_vector_type(8)));
typedef f16 f16x4 __attribute__((ext_vector_type(4)));
typedef float f32x4 __attribute__((ext_vector_type(4)));

#define MFMA_F16(a, b, c) __builtin_amdgcn_mfma_f32_16x16x32_f16((a), (b), (c), 0, 0, 0)

// ---------------------------------------------------------------------------
// async global->LDS 16B copy
// ---------------------------------------------------------------------------
__device__ __forceinline__ void ld_lds16(const void* g, void* l) {
  __builtin_amdgcn_global_load_lds((const __attribute__((address_space(1))) void*)g,
                                   (__attribute__((address_space(3))) void*)l, 16, 0, 0);
}

// ---------------------------------------------------------------------------
// cast fp32 -> fp16 for hidden (2M) + 4 weight matrices (1M each), float4-wide
// ---------------------------------------------------------------------------
__global__ __launch_bounds__(256) void cast_all(
    const float* __restrict__ hs, const float* __restrict__ wq,
    const float* __restrict__ wk, const float* __restrict__ wv,
    const float* __restrict__ wo, f16* __restrict__ hb,
    f16* __restrict__ wqb, f16* __restrict__ wkb,
    f16* __restrict__ wvb, f16* __restrict__ wob) {
  int idx = blockIdx.x * 256 + threadIdx.x;  // 1,572,864 float4 chunks total
  const float* src;
  f16* dst;
  int j;
  if (idx < 524288) {  // hidden: 2M floats / 4
    src = hs; dst = hb; j = idx;
  } else {
    int t = idx - 524288;
    int w = t >> 18;      // 262144 float4 per weight
    j = t & 262143;
    src = (w == 0) ? wq : (w == 1) ? wk : (w == 2) ? wv : wo;
    dst = (w == 0) ? wqb : (w == 1) ? wkb : (w == 2) ? wvb : wob;
  }
  float4 v = ((const float4*)src)[j];
  f16x4 o;
  o[0] = (f16)v.x; o[1] = (f16)v.y; o[2] = (f16)v.z; o[3] = (f16)v.w;
  ((f16x4*)dst)[j] = o;
}

// ---------------------------------------------------------------------------
// relative-position bias table: btab[h][rel + 2047], rel = kv - q
// ---------------------------------------------------------------------------
__global__ __launch_bounds__(256) void build_bias(const float* __restrict__ rb,
                                                  float* __restrict__ btab) {
  int idx = blockIdx.x * 256 + threadIdx.x;  // 65536 = 16 heads * 4096
  int h = idx >> 12;
  int t = idx & 4095;
  int rel = t - 2047;
  int bucket = (rel > 0) ? 16 : 0;
  int a = (rel < 0) ? -rel : rel;
  int lg;
  if (a < 8) {
    lg = a;
  } else {
    int cnt = (a >= 12) + (a >= 16) + (a >= 23) + (a >= 32) + (a >= 46) +
              (a >= 64) + (a >= 91);
    lg = 8 + cnt;  // max 15
  }
  bucket += lg;
  btab[idx] = rb[bucket * 16 + h];  // rel_bias[32][16]
}

// ---------------------------------------------------------------------------
// GEMM mainloop: C[128x128] tile of A[M,K=1024] * B[N,K=1024]^T (both row-major)
// ---------------------------------------------------------------------------
__device__ __forceinline__ void gemm_mainloop(const f16* __restrict__ A,
                                              const f16* __restrict__ B,
                                              int brow, int bcol,
                                              f16* lA, f16* lB,
                                              f32x4 acc[4][4]) {
  const int tid = threadIdx.x;
  const int lane = tid & 63;
  const int wave = tid >> 6;
  const int wm = wave >> 1, wn = wave & 1;
  const int lo = lane & 15;
  const int hi8 = (lane >> 4) << 3;
  const f16* ga = A + (size_t)(brow + (tid >> 2)) * 1024 + ((tid & 3) << 3);
  const f16* gb = B + (size_t)(bcol + (tid >> 2)) * 1024 + ((tid & 3) << 3);
  f16* la_dst = lA + tid * 8;
  f16* lb_dst = lB + tid * 8;
  for (int k0 = 0; k0 < 1024; k0 += 32) {
    ld_lds16(ga + k0,             la_dst);
    ld_lds16(ga + k0 + 64 * 1024, la_dst + 2048);
    ld_lds16(gb + k0,             lb_dst);
    ld_lds16(gb + k0 + 64 * 1024, lb_dst + 2048);
    __syncthreads();
    f16x8 af[4], bf[4];
#pragma unroll
    for (int i = 0; i < 4; ++i) {
      af[i] = *(const f16x8*)(lA + (wm * 64 + i * 16 + lo) * 32 + hi8);
      bf[i] = *(const f16x8*)(lB + (wn * 64 + i * 16 + lo) * 32 + hi8);
    }
#pragma unroll
    for (int i = 0; i < 4; ++i)
#pragma unroll
      for (int j = 0; j < 4; ++j)
        acc[i][j] = MFMA_F16(af[i], bf[j], acc[i][j]);
    __syncthreads();
  }
}

// QKV projections fused over blockIdx.z (0=Q, 1=K, 2=V-transposed)
__global__ __launch_bounds__(256) void gemm_qkv(
    const f16* __restrict__ A, const f16* __restrict__ Wq,
    const f16* __restrict__ Wk, const f16* __restrict__ Wv,
    f16* __restrict__ Qo, f16* __restrict__ Ko, f16* __restrict__ VTo) {
  __shared__ __align__(16) f16 lA[128 * 32];
  __shared__ __align__(16) f16 lB[128 * 32];
  const int z = blockIdx.z;
  const f16* B = (z == 0) ? Wq : (z == 1) ? Wk : Wv;
  const int brow = blockIdx.x * 128, bcol = blockIdx.y * 128;
  f32x4 acc[4][4];
#pragma unroll
  for (int i = 0; i < 4; ++i)
#pragma unroll
    for (int j = 0; j < 4; ++j) acc[i][j] = f32x4{0.f, 0.f, 0.f, 0.f};
  gemm_mainloop(A, B, brow, bcol, lA, lB, acc);
  const int lane = threadIdx.x & 63, wave = threadIdx.x >> 6;
  const int wm = wave >> 1, wn = wave & 1;
  const int lo = lane & 15, hi = lane >> 4;
  if (z < 2) {
    f16* C = z ? Ko : Qo;
#pragma unroll
    for (int i = 0; i < 4; ++i)
#pragma unroll
      for (int j = 0; j < 4; ++j) {
        int col = bcol + wn * 64 + j * 16 + lo;
        int row0 = brow + wm * 64 + i * 16 + hi * 4;
#pragma unroll
        for (int r = 0; r < 4; ++r)
          C[(size_t)(row0 + r) * 1024 + col] = (f16)acc[i][j][r];
      }
  } else {
    // V transposed: VT[n][s], n = h*64+dv
#pragma unroll
    for (int i = 0; i < 4; ++i)
#pragma unroll
      for (int j = 0; j < 4; ++j) {
        int col = bcol + wn * 64 + j * 16 + lo;       // n
        int row0 = brow + wm * 64 + i * 16 + hi * 4;  // s
        f16x4 v4;
#pragma unroll
        for (int r = 0; r < 4; ++r) v4[r] = (f16)acc[i][j][r];
        *(f16x4*)(VTo + (size_t)col * 2048 + row0) = v4;
      }
  }
}

// output projection: AO[2048,1024] * Wo[1024,1024]^T -> fp32 d_out
__global__ __launch_bounds__(256) void gemm_out(const f16* __restrict__ A,
                                                const f16* __restrict__ W,
                                                float* __restrict__ C) {
  __shared__ __align__(16) f16 lA[128 * 32];
  __shared__ __align__(16) f16 lB[128 * 32];
  const int brow = blockIdx.x * 128, bcol = blockIdx.y * 128;
  f32x4 acc[4][4];
#pragma unroll
  for (int i = 0; i < 4; ++i)
#pragma unroll
    for (int j = 0; j < 4; ++j) acc[i][j] = f32x4{0.f, 0.f, 0.f, 0.f};
  gemm_mainloop(A, W, brow, bcol, lA, lB, acc);
  const int lane = threadIdx.x & 63, wave = threadIdx.x >> 6;
  const int wm = wave >> 1, wn = wave & 1;
  const int lo = lane & 15, hi = lane >> 4;
#pragma unroll
  for (int i = 0; i < 4; ++i)
#pragma unroll
    for (int j = 0; j < 4; ++j) {
      int col = bcol + wn * 64 + j * 16 + lo;
      int row0 = brow + wm * 64 + i * 16 + hi * 4;
#pragma unroll
      for (int r = 0; r < 4; ++r)
        C[(size_t)(row0 + r) * 1024 + col] = acc[i][j][r];
    }
}

// ---------------------------------------------------------------------------
// Flash attention v4: LDS-staged K/V (XOR-swizzled, dbuf) + 2-deep software
// pipeline: slot t issues ds-reads + QK^T MFMAs of tile t while running
// softmax+PV of tile t-1 (independent -> compiler interleaves pipes).
// V is read LDS->regs in its own slot, consumed next slot (no 3rd buffer).
// + T5 setprio around MFMA clusters, T13 defer-max (THR=8).
// ---------------------------------------------------------------------------
__global__ __launch_bounds__(256, 2) void attn_kernel(
    const f16* __restrict__ Q, const f16* __restrict__ K,
    const f16* __restrict__ VT, const float* __restrict__ btab,
    f16* __restrict__ AO) {
  __shared__ __align__(16) f16 lK[2][4096];
  __shared__ __align__(16) f16 lV[2][4096];

  const int h = blockIdx.y;
  const int q0 = blockIdx.x * 64;
  const int tid = threadIdx.x;
  const int wave = tid >> 6, lane = tid & 63;
  const int lo = lane & 15, hi = lane >> 4;
  const int sw = lo & 7;
  const int myq = q0 + wave * 16 + lo;

  const f16* Kh = K + h * 64;
  const f16* VTh = VT + (size_t)h * 64 * 2048;
  const float* bt = btab + h * 4096 + 2047 - myq;

  // Q fragments (B-operand, cols = q): registers for whole kernel
  f16x8 qf[2];
#pragma unroll
  for (int kk = 0; kk < 2; ++kk)
    qf[kk] = *(const f16x8*)(Q + (size_t)myq * 1024 + h * 64 + kk * 32 + hi * 8);

  // staging chunk indices (2 chunks each for K and V per thread)
  const int sc0 = wave * 64 + lane;
  const int sc1 = 256 + sc0;
  const int r0 = sc0 >> 3, e0 = (sc0 & 7) ^ (r0 & 7);
  const int r1 = sc1 >> 3, e1 = (sc1 & 7) ^ (r1 & 7);

#define STAGE(bufi, kv)                                                        \
  do {                                                                         \
    ld_lds16(Kh + (size_t)((kv) + r0) * 1024 + e0 * 8, &lK[bufi][sc0 * 8]);    \
    ld_lds16(Kh + (size_t)((kv) + r1) * 1024 + e1 * 8, &lK[bufi][sc1 * 8]);    \
    ld_lds16(VTh + (size_t)r0 * 2048 + (kv) + e0 * 8, &lV[bufi][sc0 * 8]);     \
    ld_lds16(VTh + (size_t)r1 * 2048 + (kv) + e1 * 8, &lV[bufi][sc1 * 8]);     \
  } while (0)

  float m_run = -1e30f, l_run = 0.f;
  f32x4 oacc[4];
#pragma unroll
  for (int d = 0; d < 4; ++d) oacc[d] = f32x4{0.f, 0.f, 0.f, 0.f};

  // two-tile pipeline state
  f16x8 vfA[4][2], vfB[4][2];
  f32x4 saccA[4], saccB[4];
  float biasA[16], biasB[16];

// issue ds-reads (K frags + V->regs), stage next, QK^T for tile t_ into CUR
#define TILE_FRONT(t_, CUR)                                                    \
  {                                                                            \
    const int b_ = (t_) & 1;                                                   \
    const int kv0_ = (t_) * 64;                                                \
    const f16* lKb_ = lK[b_];                                                  \
    const f16* lVb_ = lV[b_];                                                  \
    f16x8 kf_[4][2];                                                           \
    _Pragma("unroll") for (int m_ = 0; m_ < 4; ++m_)                           \
      _Pragma("unroll") for (int kk_ = 0; kk_ < 2; ++kk_)                      \
        kf_[m_][kk_] = *(const f16x8*)&lKb_[(m_ * 16 + lo) * 64 +              \
                                            (((kk_ << 2) | hi) ^ sw) * 8];     \
    _Pragma("unroll") for (int d_ = 0; d_ < 4; ++d_)                           \
      _Pragma("unroll") for (int kk_ = 0; kk_ < 2; ++kk_) {                    \
        const int row_ = d_ * 16 + lo;                                         \
        const int cc_ = kk_ * 4 + (hi >> 1);                                   \
        const int ia_ = (hi & 1) * 4;                                          \
        f16x4 vlo_ = *(const f16x4*)&lVb_[row_ * 64 + (cc_ ^ sw) * 8 + ia_];   \
        f16x4 vhi_ =                                                           \
            *(const f16x4*)&lVb_[row_ * 64 + ((cc_ + 2) ^ sw) * 8 + ia_];      \
        _Pragma("unroll") for (int r_ = 0; r_ < 4; ++r_) {                     \
          vf##CUR[d_][kk_][r_] = vlo_[r_];                                     \
          vf##CUR[d_][kk_][r_ + 4] = vhi_[r_];                                 \
        }                                                                      \
      }                                                                        \
    if ((t_) < 31) STAGE(1 - b_, kv0_ + 64);                                   \
    _Pragma("unroll") for (int i_ = 0; i_ < 16; ++i_)                          \
      bias##CUR[i_] = bt[kv0_ + (i_ >> 2) * 16 + hi * 4 + (i_ & 3)];           \
    __builtin_amdgcn_s_setprio(1);                                             \
    _Pragma("unroll") for (int m_ = 0; m_ < 4; ++m_) {                         \
      sacc##CUR[m_] = f32x4{0.f, 0.f, 0.f, 0.f};                               \
      _Pragma("unroll") for (int kk_ = 0; kk_ < 2; ++kk_)                      \
        sacc##CUR[m_] = MFMA_F16(kf_[m_][kk_], qf[kk_], sacc##CUR[m_]);        \
    }                                                                          \
    __builtin_amdgcn_s_setprio(0);                                             \
  }

// softmax + PV for tile held in PRV state (updates m_run, l_run, oacc)
#define SOFTMAX_PV(PRV)                                                        \
  {                                                                            \
    float p_[16];                                                              \
    float mx_ = -1e30f;                                                        \
    _Pragma("unroll") for (int i_ = 0; i_ < 16; ++i_) {                        \
      float s_ = sacc##PRV[i_ >> 2][i_ & 3] + bias##PRV[i_];                   \
      p_[i_] = s_;                                                             \
      mx_ = fmaxf(mx_, s_);                                                    \
    }                                                                          \
    mx_ = fmaxf(mx_, __shfl_xor(mx_, 16, 64));                                 \
    mx_ = fmaxf(mx_, __shfl_xor(mx_, 32, 64));                                 \
    if (!__all(mx_ <= m_run + 8.0f)) {                                         \
      float mn_ = fmaxf(m_run, mx_);                                           \
      float sc_ = __expf(m_run - mn_);                                         \
      l_run *= sc_;                                                            \
      _Pragma("unroll") for (int d_ = 0; d_ < 4; ++d_) oacc[d_] *= sc_;        \
      m_run = mn_;                                                             \
    }                                                                          \
    float ps_ = 0.f;                                                           \
    _Pragma("unroll") for (int i_ = 0; i_ < 16; ++i_) {                        \
      p_[i_] = __expf(p_[i_] - m_run);                                         \
      ps_ += p_[i_];                                                           \
    }                                                                          \
    ps_ += __shfl_xor(ps_, 16, 64);                                            \
    ps_ += __shfl_xor(ps_, 32, 64);                                            \
    l_run += ps_;                                                              \
    f16x8 pf_[2];                                                              \
    _Pragma("unroll") for (int kk_ = 0; kk_ < 2; ++kk_)                        \
      _Pragma("unroll") for (int j_ = 0; j_ < 8; ++j_)                         \
        pf_[kk_][j_] = (f16)p_[(kk_ * 2 + (j_ >> 2)) * 4 + (j_ & 3)];          \
    __builtin_amdgcn_s_setprio(1);                                             \
    _Pragma("unroll") for (int d_ = 0; d_ < 4; ++d_)                           \
      _Pragma("unroll") for (int kk_ = 0; kk_ < 2; ++kk_)                      \
        oacc[d_] = MFMA_F16(vf##PRV[d_][kk_], pf_[kk_], oacc[d_]);             \
    __builtin_amdgcn_s_setprio(0);                                             \
  }

  STAGE(0, 0);
  __syncthreads();

  // slot 0: front of tile 0 (state A)
  TILE_FRONT(0, A);
  __syncthreads();

  for (int k2 = 0; k2 < 15; ++k2) {
    const int t1 = 2 * k2 + 1;  // 1,3,...,29
    TILE_FRONT(t1, B);
    SOFTMAX_PV(A);
    __syncthreads();
    TILE_FRONT(t1 + 1, A);  // 2,4,...,30
    SOFTMAX_PV(B);
    __syncthreads();
  }
  // slot 31: front of tile 31 (B), finish tile 30 (A)
  TILE_FRONT(31, B);
  SOFTMAX_PV(A);
  // finish tile 31
  SOFTMAX_PV(B);

#undef TILE_FRONT
#undef SOFTMAX_PV
#undef STAGE

  // ---- epilogue: O[dv][q] / l -> AO[s][h*64+dv] ----
  float inv = 1.f / l_run;
#pragma unroll
  for (int d = 0; d < 4; ++d) {
    f16x4 ov;
#pragma unroll
    for (int r = 0; r < 4; ++r) ov[r] = (f16)(oacc[d][r] * inv);
    *(f16x4*)(AO + (size_t)myq * 1024 + h * 64 + d * 16 + hi * 4) = ov;
  }
}

// ---------------------------------------------------------------------------
extern "C" void kernel_launch(void* const* d_in, const int* in_sizes, int n_in,
                              void* d_out, int out_size, void* d_ws, size_t ws_size,
                              hipStream_t stream) {
  const float* hs = (const float*)d_in[0];
  const float* wq = (const float*)d_in[1];
  const float* wk = (const float*)d_in[2];
  const float* wv = (const float*)d_in[3];
  const float* wo = (const float*)d_in[4];
  const float* rb = (const float*)d_in[5];

  char* w = (char*)d_ws;
  f16* hb  = (f16*)w; w += (size_t)2048 * 1024 * 2;
  f16* wqb = (f16*)w; w += (size_t)1024 * 1024 * 2;
  f16* wkb = (f16*)w; w += (size_t)1024 * 1024 * 2;
  f16* wvb = (f16*)w; w += (size_t)1024 * 1024 * 2;
  f16* wob = (f16*)w; w += (size_t)1024 * 1024 * 2;
  f16* Qb  = (f16*)w; w += (size_t)2048 * 1024 * 2;
  f16* Kb  = (f16*)w; w += (size_t)2048 * 1024 * 2;
  f16* VTb = (f16*)w; w += (size_t)2048 * 1024 * 2;
  f16* AOb = (f16*)w; w += (size_t)2048 * 1024 * 2;
  float* btab = (float*)w; w += (size_t)16 * 4096 * 4;

  cast_all<<<6144, 256, 0, stream>>>(hs, wq, wk, wv, wo, hb, wqb, wkb, wvb, wob);
  build_bias<<<256, 256, 0, stream>>>(rb, btab);
  gemm_qkv<<<dim3(16, 8, 3), 256, 0, stream>>>(hb, wqb, wkb, wvb, Qb, Kb, VTb);
  attn_kernel<<<dim3(32, 16), 256, 0, stream>>>(Qb, Kb, VTb, btab, AOb);
  gemm_out<<<dim3(16, 8), 256, 0, stream>>>(AOb, wob, (float*)d_out);
}

// Round 5
// 98.350 us; speedup vs baseline: 2.5881x; 1.1097x over previous
//
#include <hip/hip_runtime.h>
#include <hip/hip_bf16.h>

typedef _Float16 f16;
typedef f16 f16x8 __attribute__((ext_vector_type(8)));
typedef f16 f16x4 __attribute__((ext_vector_type(4)));
typedef float f32x4 __attribute__((ext_vector_type(4)));

#define MFMA_F16(a, b, c) __builtin_amdgcn_mfma_f32_16x16x32_f16((a), (b), (c), 0, 0, 0)

// ---------------------------------------------------------------------------
// async global->LDS 16B copy
// ---------------------------------------------------------------------------
__device__ __forceinline__ void ld_lds16(const void* g, void* l) {
  __builtin_amdgcn_global_load_lds((const __attribute__((address_space(1))) void*)g,
                                   (__attribute__((address_space(3))) void*)l, 16, 0, 0);
}

// ---------------------------------------------------------------------------
// cast fp32 -> fp16 for hidden (2M) + 4 weight matrices (1M each), float4-wide
// ---------------------------------------------------------------------------
__global__ __launch_bounds__(256) void cast_all(
    const float* __restrict__ hs, const float* __restrict__ wq,
    const float* __restrict__ wk, const float* __restrict__ wv,
    const float* __restrict__ wo, f16* __restrict__ hb,
    f16* __restrict__ wqb, f16* __restrict__ wkb,
    f16* __restrict__ wvb, f16* __restrict__ wob) {
  int idx = blockIdx.x * 256 + threadIdx.x;  // 1,572,864 float4 chunks total
  const float* src;
  f16* dst;
  int j;
  if (idx < 524288) {  // hidden: 2M floats / 4
    src = hs; dst = hb; j = idx;
  } else {
    int t = idx - 524288;
    int w = t >> 18;      // 262144 float4 per weight
    j = t & 262143;
    src = (w == 0) ? wq : (w == 1) ? wk : (w == 2) ? wv : wo;
    dst = (w == 0) ? wqb : (w == 1) ? wkb : (w == 2) ? wvb : wob;
  }
  float4 v = ((const float4*)src)[j];
  f16x4 o;
  o[0] = (f16)v.x; o[1] = (f16)v.y; o[2] = (f16)v.z; o[3] = (f16)v.w;
  ((f16x4*)dst)[j] = o;
}

// ---------------------------------------------------------------------------
// relative-position bias table: btab[h][rel + 2047], rel = kv - q
// ---------------------------------------------------------------------------
__global__ __launch_bounds__(256) void build_bias(const float* __restrict__ rb,
                                                  float* __restrict__ btab) {
  int idx = blockIdx.x * 256 + threadIdx.x;  // 65536 = 16 heads * 4096
  int h = idx >> 12;
  int t = idx & 4095;
  int rel = t - 2047;
  int bucket = (rel > 0) ? 16 : 0;
  int a = (rel < 0) ? -rel : rel;
  int lg;
  if (a < 8) {
    lg = a;
  } else {
    int cnt = (a >= 12) + (a >= 16) + (a >= 23) + (a >= 32) + (a >= 46) +
              (a >= 64) + (a >= 91);
    lg = 8 + cnt;  // max 15
  }
  bucket += lg;
  btab[idx] = rb[bucket * 16 + h];  // rel_bias[32][16]
}

// ---------------------------------------------------------------------------
// GEMM mainloop: C[64x128] tile of A[M,1024] * B[N,1024]^T (both row-major).
// 256 threads = 4 waves (1x4 over N); wave owns 64x32 out = 4x2 frags.
// BK=64; LDS XOR-swizzled (chunk ^= row&7) via pre-swizzled global source +
// swizzled ds_read (both-sides, global_load_lds writes linearly).
// ---------------------------------------------------------------------------
__device__ __forceinline__ void gemm_mainloop(const f16* __restrict__ A,
                                              const f16* __restrict__ B,
                                              int brow, int bcol,
                                              f16* lA, f16* lB,
                                              f32x4 acc[4][2]) {
  const int tid = threadIdx.x;
  const int lane = tid & 63;
  const int wn = tid >> 6;
  const int lo = lane & 15;
  const int hi = lane >> 4;
  const int sw = lo & 7;
  // staging: rows sr (+32k), swizzled col chunk
  const int sr = tid >> 3;                       // 0..31
  const int se = (((tid & 7) ^ (sr & 7)) << 3);  // global col elem offset
  const f16* gA = A + (size_t)(brow + sr) * 1024 + se;
  const f16* gB = B + (size_t)(bcol + sr) * 1024 + se;
  f16* laD = lA + tid * 8;
  f16* lbD = lB + tid * 8;
  for (int k0 = 0; k0 < 1024; k0 += 64) {
    ld_lds16(gA + k0,             laD);
    ld_lds16(gA + k0 + 32 * 1024, laD + 2048);
    ld_lds16(gB + k0,             lbD);
    ld_lds16(gB + k0 + 32 * 1024, lbD + 2048);
    ld_lds16(gB + k0 + 64 * 1024, lbD + 4096);
    ld_lds16(gB + k0 + 96 * 1024, lbD + 6144);
    __syncthreads();
    f16x8 af[4][2], bf[2][2];
#pragma unroll
    for (int m = 0; m < 4; ++m)
#pragma unroll
      for (int ks = 0; ks < 2; ++ks)
        af[m][ks] = *(const f16x8*)(lA + (m * 16 + lo) * 64 +
                                    (((ks << 2) | hi) ^ sw) * 8);
#pragma unroll
    for (int j = 0; j < 2; ++j)
#pragma unroll
      for (int ks = 0; ks < 2; ++ks)
        bf[j][ks] = *(const f16x8*)(lB + (wn * 32 + j * 16 + lo) * 64 +
                                    (((ks << 2) | hi) ^ sw) * 8);
#pragma unroll
    for (int m = 0; m < 4; ++m)
#pragma unroll
      for (int j = 0; j < 2; ++j)
#pragma unroll
        for (int ks = 0; ks < 2; ++ks)
          acc[m][j] = MFMA_F16(af[m][ks], bf[j][ks], acc[m][j]);
    __syncthreads();
  }
}

// QKV projections fused over blockIdx.z (0=Q, 1=K, 2=V-transposed)
__global__ __launch_bounds__(256) void gemm_qkv(
    const f16* __restrict__ A, const f16* __restrict__ Wq,
    const f16* __restrict__ Wk, const f16* __restrict__ Wv,
    f16* __restrict__ Qo, f16* __restrict__ Ko, f16* __restrict__ VTo) {
  __shared__ __align__(16) f16 lA[64 * 64];
  __shared__ __align__(16) f16 lB[128 * 64];
  const int z = blockIdx.z;
  const f16* B = (z == 0) ? Wq : (z == 1) ? Wk : Wv;
  const int brow = blockIdx.x * 64, bcol = blockIdx.y * 128;
  f32x4 acc[4][2];
#pragma unroll
  for (int m = 0; m < 4; ++m)
#pragma unroll
    for (int j = 0; j < 2; ++j) acc[m][j] = f32x4{0.f, 0.f, 0.f, 0.f};
  gemm_mainloop(A, B, brow, bcol, lA, lB, acc);
  const int lane = threadIdx.x & 63, wn = threadIdx.x >> 6;
  const int lo = lane & 15, hi = lane >> 4;
  if (z < 2) {
    f16* C = z ? Ko : Qo;
#pragma unroll
    for (int m = 0; m < 4; ++m)
#pragma unroll
      for (int j = 0; j < 2; ++j) {
        int col = bcol + wn * 32 + j * 16 + lo;
        int row0 = brow + m * 16 + hi * 4;
#pragma unroll
        for (int r = 0; r < 4; ++r)
          C[(size_t)(row0 + r) * 1024 + col] = (f16)acc[m][j][r];
      }
  } else {
    // V transposed: VT[n][s], n = h*64+dv
#pragma unroll
    for (int m = 0; m < 4; ++m)
#pragma unroll
      for (int j = 0; j < 2; ++j) {
        int col = bcol + wn * 32 + j * 16 + lo;   // n
        int row0 = brow + m * 16 + hi * 4;        // s
        f16x4 v4;
#pragma unroll
        for (int r = 0; r < 4; ++r) v4[r] = (f16)acc[m][j][r];
        *(f16x4*)(VTo + (size_t)col * 2048 + row0) = v4;
      }
  }
}

// output projection: AO[2048,1024] * Wo[1024,1024]^T -> fp32 d_out
__global__ __launch_bounds__(256) void gemm_out(const f16* __restrict__ A,
                                                const f16* __restrict__ W,
                                                float* __restrict__ C) {
  __shared__ __align__(16) f16 lA[64 * 64];
  __shared__ __align__(16) f16 lB[128 * 64];
  const int brow = blockIdx.x * 64, bcol = blockIdx.y * 128;
  f32x4 acc[4][2];
#pragma unroll
  for (int m = 0; m < 4; ++m)
#pragma unroll
    for (int j = 0; j < 2; ++j) acc[m][j] = f32x4{0.f, 0.f, 0.f, 0.f};
  gemm_mainloop(A, W, brow, bcol, lA, lB, acc);
  const int lane = threadIdx.x & 63, wn = threadIdx.x >> 6;
  const int lo = lane & 15, hi = lane >> 4;
#pragma unroll
  for (int m = 0; m < 4; ++m)
#pragma unroll
    for (int j = 0; j < 2; ++j) {
      int col = bcol + wn * 32 + j * 16 + lo;
      int row0 = brow + m * 16 + hi * 4;
#pragma unroll
      for (int r = 0; r < 4; ++r)
        C[(size_t)(row0 + r) * 1024 + col] = acc[m][j][r];
    }
}

// ---------------------------------------------------------------------------
// Flash attention v4: LDS-staged K/V (XOR-swizzled, dbuf) + 2-deep software
// pipeline + setprio + defer-max. (Unchanged from round 4.)
// ---------------------------------------------------------------------------
__global__ __launch_bounds__(256, 2) void attn_kernel(
    const f16* __restrict__ Q, const f16* __restrict__ K,
    const f16* __restrict__ VT, const float* __restrict__ btab,
    f16* __restrict__ AO) {
  __shared__ __align__(16) f16 lK[2][4096];
  __shared__ __align__(16) f16 lV[2][4096];

  const int h = blockIdx.y;
  const int q0 = blockIdx.x * 64;
  const int tid = threadIdx.x;
  const int wave = tid >> 6, lane = tid & 63;
  const int lo = lane & 15, hi = lane >> 4;
  const int sw = lo & 7;
  const int myq = q0 + wave * 16 + lo;

  const f16* Kh = K + h * 64;
  const f16* VTh = VT + (size_t)h * 64 * 2048;
  const float* bt = btab + h * 4096 + 2047 - myq;

  f16x8 qf[2];
#pragma unroll
  for (int kk = 0; kk < 2; ++kk)
    qf[kk] = *(const f16x8*)(Q + (size_t)myq * 1024 + h * 64 + kk * 32 + hi * 8);

  const int sc0 = wave * 64 + lane;
  const int sc1 = 256 + sc0;
  const int r0 = sc0 >> 3, e0 = (sc0 & 7) ^ (r0 & 7);
  const int r1 = sc1 >> 3, e1 = (sc1 & 7) ^ (r1 & 7);

#define STAGE(bufi, kv)                                                        \
  do {                                                                         \
    ld_lds16(Kh + (size_t)((kv) + r0) * 1024 + e0 * 8, &lK[bufi][sc0 * 8]);    \
    ld_lds16(Kh + (size_t)((kv) + r1) * 1024 + e1 * 8, &lK[bufi][sc1 * 8]);    \
    ld_lds16(VTh + (size_t)r0 * 2048 + (kv) + e0 * 8, &lV[bufi][sc0 * 8]);     \
    ld_lds16(VTh + (size_t)r1 * 2048 + (kv) + e1 * 8, &lV[bufi][sc1 * 8]);     \
  } while (0)

  float m_run = -1e30f, l_run = 0.f;
  f32x4 oacc[4];
#pragma unroll
  for (int d = 0; d < 4; ++d) oacc[d] = f32x4{0.f, 0.f, 0.f, 0.f};

  f16x8 vfA[4][2], vfB[4][2];
  f32x4 saccA[4], saccB[4];
  float biasA[16], biasB[16];

#define TILE_FRONT(t_, CUR)                                                    \
  {                                                                            \
    const int b_ = (t_) & 1;                                                   \
    const int kv0_ = (t_) * 64;                                                \
    const f16* lKb_ = lK[b_];                                                  \
    const f16* lVb_ = lV[b_];                                                  \
    f16x8 kf_[4][2];                                                           \
    _Pragma("unroll") for (int m_ = 0; m_ < 4; ++m_)                           \
      _Pragma("unroll") for (int kk_ = 0; kk_ < 2; ++kk_)                      \
        kf_[m_][kk_] = *(const f16x8*)&lKb_[(m_ * 16 + lo) * 64 +              \
                                            (((kk_ << 2) | hi) ^ sw) * 8];     \
    _Pragma("unroll") for (int d_ = 0; d_ < 4; ++d_)                           \
      _Pragma("unroll") for (int kk_ = 0; kk_ < 2; ++kk_) {                    \
        const int row_ = d_ * 16 + lo;                                         \
        const int cc_ = kk_ * 4 + (hi >> 1);                                   \
        const int ia_ = (hi & 1) * 4;                                          \
        f16x4 vlo_ = *(const f16x4*)&lVb_[row_ * 64 + (cc_ ^ sw) * 8 + ia_];   \
        f16x4 vhi_ =                                                           \
            *(const f16x4*)&lVb_[row_ * 64 + ((cc_ + 2) ^ sw) * 8 + ia_];      \
        _Pragma("unroll") for (int r_ = 0; r_ < 4; ++r_) {                     \
          vf##CUR[d_][kk_][r_] = vlo_[r_];                                     \
          vf##CUR[d_][kk_][r_ + 4] = vhi_[r_];                                 \
        }                                                                      \
      }                                                                        \
    if ((t_) < 31) STAGE(1 - b_, kv0_ + 64);                                   \
    _Pragma("unroll") for (int i_ = 0; i_ < 16; ++i_)                          \
      bias##CUR[i_] = bt[kv0_ + (i_ >> 2) * 16 + hi * 4 + (i_ & 3)];           \
    __builtin_amdgcn_s_setprio(1);                                             \
    _Pragma("unroll") for (int m_ = 0; m_ < 4; ++m_) {                         \
      sacc##CUR[m_] = f32x4{0.f, 0.f, 0.f, 0.f};                               \
      _Pragma("unroll") for (int kk_ = 0; kk_ < 2; ++kk_)                      \
        sacc##CUR[m_] = MFMA_F16(kf_[m_][kk_], qf[kk_], sacc##CUR[m_]);        \
    }                                                                          \
    __builtin_amdgcn_s_setprio(0);                                             \
  }

#define SOFTMAX_PV(PRV)                                                        \
  {                                                                            \
    float p_[16];                                                              \
    float mx_ = -1e30f;                                                        \
    _Pragma("unroll") for (int i_ = 0; i_ < 16; ++i_) {                        \
      float s_ = sacc##PRV[i_ >> 2][i_ & 3] + bias##PRV[i_];                   \
      p_[i_] = s_;                                                             \
      mx_ = fmaxf(mx_, s_);                                                    \
    }                                                                          \
    mx_ = fmaxf(mx_, __shfl_xor(mx_, 16, 64));                                 \
    mx_ = fmaxf(mx_, __shfl_xor(mx_, 32, 64));                                 \
    if (!__all(mx_ <= m_run + 8.0f)) {                                         \
      float mn_ = fmaxf(m_run, mx_);                                           \
      float sc_ = __expf(m_run - mn_);                                         \
      l_run *= sc_;                                                            \
      _Pragma("unroll") for (int d_ = 0; d_ < 4; ++d_) oacc[d_] *= sc_;        \
      m_run = mn_;                                                             \
    }                                                                          \
    float ps_ = 0.f;                                                           \
    _Pragma("unroll") for (int i_ = 0; i_ < 16; ++i_) {                        \
      p_[i_] = __expf(p_[i_] - m_run);                                         \
      ps_ += p_[i_];                                                           \
    }                                                                          \
    ps_ += __shfl_xor(ps_, 16, 64);                                            \
    ps_ += __shfl_xor(ps_, 32, 64);                                            \
    l_run += ps_;                                                              \
    f16x8 pf_[2];                                                              \
    _Pragma("unroll") for (int kk_ = 0; kk_ < 2; ++kk_)                        \
      _Pragma("unroll") for (int j_ = 0; j_ < 8; ++j_)                         \
        pf_[kk_][j_] = (f16)p_[(kk_ * 2 + (j_ >> 2)) * 4 + (j_ & 3)];          \
    __builtin_amdgcn_s_setprio(1);                                             \
    _Pragma("unroll") for (int d_ = 0; d_ < 4; ++d_)                           \
      _Pragma("unroll") for (int kk_ = 0; kk_ < 2; ++kk_)                      \
        oacc[d_] = MFMA_F16(vf##PRV[d_][kk_], pf_[kk_], oacc[d_]);             \
    __builtin_amdgcn_s_setprio(0);                                             \
  }

  STAGE(0, 0);
  __syncthreads();

  TILE_FRONT(0, A);
  __syncthreads();

  for (int k2 = 0; k2 < 15; ++k2) {
    const int t1 = 2 * k2 + 1;
    TILE_FRONT(t1, B);
    SOFTMAX_PV(A);
    __syncthreads();
    TILE_FRONT(t1 + 1, A);
    SOFTMAX_PV(B);
    __syncthreads();
  }
  TILE_FRONT(31, B);
  SOFTMAX_PV(A);
  SOFTMAX_PV(B);

#undef TILE_FRONT
#undef SOFTMAX_PV
#undef STAGE

  float inv = 1.f / l_run;
#pragma unroll
  for (int d = 0; d < 4; ++d) {
    f16x4 ov;
#pragma unroll
    for (int r = 0; r < 4; ++r) ov[r] = (f16)(oacc[d][r] * inv);
    *(f16x4*)(AO + (size_t)myq * 1024 + h * 64 + d * 16 + hi * 4) = ov;
  }
}

// ---------------------------------------------------------------------------
extern "C" void kernel_launch(void* const* d_in, const int* in_sizes, int n_in,
                              void* d_out, int out_size, void* d_ws, size_t ws_size,
                              hipStream_t stream) {
  const float* hs = (const float*)d_in[0];
  const float* wq = (const float*)d_in[1];
  const float* wk = (const float*)d_in[2];
  const float* wv = (const float*)d_in[3];
  const float* wo = (const float*)d_in[4];
  const float* rb = (const float*)d_in[5];

  char* w = (char*)d_ws;
  f16* hb  = (f16*)w; w += (size_t)2048 * 1024 * 2;
  f16* wqb = (f16*)w; w += (size_t)1024 * 1024 * 2;
  f16* wkb = (f16*)w; w += (size_t)1024 * 1024 * 2;
  f16* wvb = (f16*)w; w += (size_t)1024 * 1024 * 2;
  f16* wob = (f16*)w; w += (size_t)1024 * 1024 * 2;
  f16* Qb  = (f16*)w; w += (size_t)2048 * 1024 * 2;
  f16* Kb  = (f16*)w; w += (size_t)2048 * 1024 * 2;
  f16* VTb = (f16*)w; w += (size_t)2048 * 1024 * 2;
  f16* AOb = (f16*)w; w += (size_t)2048 * 1024 * 2;
  float* btab = (float*)w; w += (size_t)16 * 4096 * 4;

  cast_all<<<6144, 256, 0, stream>>>(hs, wq, wk, wv, wo, hb, wqb, wkb, wvb, wob);
  build_bias<<<256, 256, 0, stream>>>(rb, btab);
  gemm_qkv<<<dim3(32, 8, 3), 256, 0, stream>>>(hb, wqb, wkb, wvb, Qb, Kb, VTb);
  attn_kernel<<<dim3(32, 16), 256, 0, stream>>>(Qb, Kb, VTb, btab, AOb);
  gemm_out<<<dim3(32, 8), 256, 0, stream>>>(AOb, wob, (float*)d_out);
}